// Round 3
// baseline (398.467 us; speedup 1.0000x reference)
//
#include <hip/hip_runtime.h>
#include <math.h>

#define F_DIM 32
#define A_DIM 8
#define T_DIM 400
#define MT 512
#define PTS 256

static __device__ __forceinline__ float az_step()     { return 0.78539816339744830962f; } // pi/4
static __device__ __forceinline__ float pi_f()        { return 3.14159265358979323846f; }
static __device__ __forceinline__ float inv_sin_om()  { return 1.41421356237309504880f; } // 1/sin(pi/4)
static __device__ __forceinline__ float four_ov_pi()  { return 1.27323954473516268615f; }

static __device__ __forceinline__ unsigned short f2b(float f) {
    unsigned int x = __float_as_uint(f);
    unsigned int r = (x + 0x7FFFu + ((x >> 16) & 1u)) >> 16; // round-to-nearest-even
    return (unsigned short)r;
}

// ---------------- transpose+quantize (F, M) f32 -> (M, F) bf16 ----------------
// m-tile 512: each 32-lane half-wave reads a 512-B contiguous run of ONE f-row
// per instruction (vs 128 B before). bf16 LDS tile, 512 B/wave-instr stores.
__global__ __launch_bounds__(256) void transpose_bf16_kernel(const float* __restrict__ src,
                                                             unsigned short* __restrict__ dst,
                                                             int M) {
    __shared__ unsigned short tile[F_DIM][MT + 2]; // word-stride 257 == 1 mod 32 -> 2-way max
    const int m0 = blockIdx.x * MT;
    const int t = threadIdx.x;
    const int w = t >> 6;           // wave 0..3
    const int h = (t >> 5) & 1;     // half-wave
    const int sub = t & 31;         // sub-lane
#pragma unroll
    for (int i = 0; i < 4; ++i) {
        int f = 2 * w + h + 8 * i;
        const float* rp = src + (size_t)f * M + m0;
#pragma unroll
        for (int c = 0; c < 4; ++c) {
            int m = c * 128 + sub * 4;
            float4 v = *(const float4*)(rp + m);
            ushort4 o;
            o.x = f2b(v.x); o.y = f2b(v.y); o.z = f2b(v.z); o.w = f2b(v.w);
            *(ushort4*)&tile[f][m] = o;
        }
    }
    __syncthreads();
    const int fi = (t & 7) * 4;
    const int mb = t >> 3;          // 0..31
#pragma unroll
    for (int it = 0; it < 16; ++it) {
        int m = mb + 32 * it;
        ushort4 o;
        o.x = tile[fi][m]; o.y = tile[fi + 1][m]; o.z = tile[fi + 2][m]; o.w = tile[fi + 3][m];
        *(ushort4*)(dst + (size_t)(m0 + m) * F_DIM + fi) = o;
    }
}

// ---------------- per-point parameter math (matches torch.bucketize / ref) ----------------
struct PtParams {
    int   base[4];   // (a_l,il0) (a_l,ir0) (a_r,il0) (a_r,ir0), element index incl. *F
    int   d1;        // (ir1-il1)*F  (0 or F)
    float wA[4];     // {w1*ul, w1*ur, w2*ul, w2*ur}
    float vl, vr;
};

static __device__ __forceinline__ PtParams compute_params(float x, float y, float d) {
    PtParams P;
    // axis 0
    int ir0 = (int)ceilf(x * 4.0f); if (ir0 > T_DIM - 1) ir0 = T_DIM - 1; if (ir0 < 0) ir0 = 0;
    int il0 = ir0 - 1; if (il0 < 0) il0 = 0;
    float dl0 = fmaxf(x - (float)il0 * 0.25f, 0.0f);
    float dr0 = fmaxf((float)ir0 * 0.25f - x, 0.0f);
    if (dl0 == 0.0f && dr0 == 0.0f) { dl0 = 1.0f; dr0 = 1.0f; }
    float inv0 = 1.0f / (dl0 + dr0);
    float ul = dr0 * inv0, ur = dl0 * inv0;
    // axis 1
    int ir1 = (int)ceilf(y * 4.0f); if (ir1 > T_DIM - 1) ir1 = T_DIM - 1; if (ir1 < 0) ir1 = 0;
    int il1 = ir1 - 1; if (il1 < 0) il1 = 0;
    float dl1 = fmaxf(y - (float)il1 * 0.25f, 0.0f);
    float dr1 = fmaxf((float)ir1 * 0.25f - y, 0.0f);
    if (dl1 == 0.0f && dr1 == 0.0f) { dl1 = 1.0f; dr1 = 1.0f; }
    float inv1 = 1.0f / (dl1 + dr1);
    P.vl = dr1 * inv1; P.vr = dl1 * inv1;
    // azimuth
    int k = (int)floorf((d + pi_f()) * four_ov_pi());
    if (k < 0) k = 0; if (k > A_DIM - 1) k = A_DIM - 1;
    int al = k, ar = (k + 1) & (A_DIM - 1);
    float theta = fmaxf(d - (-pi_f() + (float)k * az_step()), 0.0f);
    float w1 = sinf(az_step() - theta) * inv_sin_om();
    float w2 = sinf(theta) * inv_sin_om();
    P.wA[0] = w1 * ul; P.wA[1] = w1 * ur;
    P.wA[2] = w2 * ul; P.wA[3] = w2 * ur;
    P.base[0] = ((al * T_DIM + il0) * T_DIM + il1) * F_DIM;
    P.base[1] = ((al * T_DIM + ir0) * T_DIM + il1) * F_DIM;
    P.base[2] = ((ar * T_DIM + il0) * T_DIM + il1) * F_DIM;
    P.base[3] = ((ar * T_DIM + ir0) * T_DIM + il1) * F_DIM;
    P.d1 = (ir1 - il1) * F_DIM;
    return P;
}

// ---------------- main gather kernel (transposed bf16 table) ----------------
// 256 points/block. Params: 1 thread/point. Gather: 16 lanes/point, uint2 (4 bf16)
// per lane -> 512 B per wave-load; shfl_xor(8) folds the (i1,i1+1) halves.
__global__ __launch_bounds__(256) void interp_kernel(const float* __restrict__ pos,
                                                     const float* __restrict__ dirs,
                                                     const unsigned short* __restrict__ Gt,
                                                     float* __restrict__ out, int N) {
    __shared__ int   s_base[PTS][4];
    __shared__ int   s_d1[PTS];
    __shared__ float s_w[PTS][4][2];  // wA[j] * {vl, vr}
    __shared__ float s_tile[PTS][33];

    const int n0 = blockIdx.x * PTS;
    const int t = threadIdx.x;

    {
        int n = n0 + t;
        float x = 0.0f, y = 0.0f, d = 0.0f;
        if (n < N) {
            float2 p2 = ((const float2*)pos)[n];
            x = p2.x; y = p2.y;
            d = dirs[n];
        }
        PtParams P = compute_params(x, y, d);
#pragma unroll
        for (int j = 0; j < 4; ++j) {
            s_base[t][j] = P.base[j];
            s_w[t][j][0] = P.wA[j] * P.vl;
            s_w[t][j][1] = P.wA[j] * P.vr;
        }
        s_d1[t] = P.d1;
    }
    __syncthreads();

    const int g    = t >> 4;        // group 0..15
    const int l    = t & 15;        // lane within group
    const int side = l >> 3;        // 0: row i1, 1: row i1+1
    const int fo   = (l & 7) * 4;   // feature offset (4 bf16 per lane)

#pragma unroll 4
    for (int it = 0; it < 16; ++it) {
        int p = it * 16 + g;
        int dd = side ? s_d1[p] : 0;
        float a0 = 0.0f, a1 = 0.0f, a2 = 0.0f, a3 = 0.0f;
#pragma unroll
        for (int j = 0; j < 4; ++j) {
            uint2 u = *(const uint2*)(Gt + (s_base[p][j] + dd + fo));
            float w = s_w[p][j][side];
            a0 = fmaf(w, __uint_as_float(u.x << 16),          a0);
            a1 = fmaf(w, __uint_as_float(u.x & 0xffff0000u),  a1);
            a2 = fmaf(w, __uint_as_float(u.y << 16),          a2);
            a3 = fmaf(w, __uint_as_float(u.y & 0xffff0000u),  a3);
        }
        a0 += __shfl_xor(a0, 8);
        a1 += __shfl_xor(a1, 8);
        a2 += __shfl_xor(a2, 8);
        a3 += __shfl_xor(a3, 8);
        if (side == 0) {           // scalar b32 writes: conflict-free with stride 33
            s_tile[p][fo]     = a0;
            s_tile[p][fo + 1] = a1;
            s_tile[p][fo + 2] = a2;
            s_tile[p][fo + 3] = a3;
        }
    }
    __syncthreads();

    int n = n0 + t;
    if (n < N) {
#pragma unroll
        for (int f = 0; f < F_DIM; ++f)
            out[(size_t)f * N + n] = s_tile[t][f];
    }
}

// ---------------- fallback: direct gather from original layout ----------------
__global__ __launch_bounds__(256) void direct_kernel(const float* __restrict__ pos,
                                                     const float* __restrict__ dirs,
                                                     const float* __restrict__ grid,
                                                     float* __restrict__ out, int N) {
    int n = blockIdx.x * blockDim.x + threadIdx.x;
    if (n >= N) return;
    float2 p = ((const float2*)pos)[n];
    PtParams P = compute_params(p.x, p.y, dirs[n]);
    int b[4], d1 = P.d1 / F_DIM;
#pragma unroll
    for (int j = 0; j < 4; ++j) b[j] = P.base[j] / F_DIM;
    const int fstride = A_DIM * T_DIM * T_DIM;
    for (int f = 0; f < F_DIM; ++f) {
        const float* gf = grid + (size_t)f * fstride;
        float acc = 0.0f;
#pragma unroll
        for (int j = 0; j < 4; ++j) {
            float w = P.wA[j];
            acc = fmaf(w * P.vl, gf[b[j]],      acc);
            acc = fmaf(w * P.vr, gf[b[j] + d1], acc);
        }
        out[(size_t)f * N + n] = acc;
    }
}

extern "C" void kernel_launch(void* const* d_in, const int* in_sizes, int n_in,
                              void* d_out, int out_size, void* d_ws, size_t ws_size,
                              hipStream_t stream) {
    const float* pos  = (const float*)d_in[0];
    const float* dirs = (const float*)d_in[1];
    const float* grid = (const float*)d_in[2];
    float* out = (float*)d_out;
    const int N = in_sizes[1];

    const size_t needed = (size_t)A_DIM * T_DIM * T_DIM * F_DIM * sizeof(unsigned short);
    if (ws_size >= needed) {
        unsigned short* Gt = (unsigned short*)d_ws;
        const int M = A_DIM * T_DIM * T_DIM; // 1,280,000 — divisible by 512
        transpose_bf16_kernel<<<M / MT, 256, 0, stream>>>(grid, Gt, M);
        interp_kernel<<<(N + PTS - 1) / PTS, 256, 0, stream>>>(pos, dirs, Gt, out, N);
    } else {
        direct_kernel<<<(N + 255) / 256, 256, 0, stream>>>(pos, dirs, grid, out, N);
    }
}